// Round 1
// baseline (1759.437 us; speedup 1.0000x reference)
//
#include <hip/hip_runtime.h>
#include <math.h>

// Problem constants (B=1)
#define S_LEN 4096
#define DIN   512
#define NH    8
#define DK    64
#define DV    64
#define DOUT  512

// ---------------------------------------------------------------------------
// Swizzled 64x64 fp32 LDS tile: row stride 64 (no pad), 4-element groups
// rotated by (row>>2) so that column-ish accesses spread across bank groups.
// float4 accesses at col%4==0 stay 16B-aligned.
// ---------------------------------------------------------------------------
__device__ __forceinline__ int swz(int row, int col) {
    return (row << 6) + (((((col >> 2) + (row >> 2)) & 15) << 2) | (col & 3));
}

// ---------------------------------------------------------------------------
// Generic 64-wide tile GEMM body: C[s, n] = sum_k A[s,k] * B[k,n]
// Block = 256 threads, computes a 64(s) x 64(n) tile of C at s-block `sblk`.
// B is staged transposed into LDS (Wt[n][k]) so the inner loop is an
// inner-product over k with float4 LDS reads on both operands.
// ---------------------------------------------------------------------------
__device__ __forceinline__ void gemm_tile(
    const float* __restrict__ A, const float* __restrict__ Bm, float* __restrict__ C,
    int lda, int ldb, int ldc, int Kdim, int sblk, float* Xs, float* Wt)
{
    const int t  = threadIdx.x;
    const int tc = t & 15;    // output column group (4 cols)
    const int tr = t >> 4;    // output row group (4 rows)

    float acc[4][4];
#pragma unroll
    for (int i = 0; i < 4; ++i)
#pragma unroll
        for (int j = 0; j < 4; ++j) acc[i][j] = 0.f;

    for (int k0 = 0; k0 < Kdim; k0 += 64) {
        // stage A tile [64 s x 64 k], coalesced float4 loads
        {
            const int col4 = (t & 15) << 2;
            const int rowb = t >> 4;
#pragma unroll
            for (int p = 0; p < 4; ++p) {
                const int row = rowb + p * 16;
                const float4 v = *(const float4*)&A[(size_t)(sblk * 64 + row) * lda + k0 + col4];
                *(float4*)&Xs[swz(row, col4)] = v;
            }
        }
        // stage B transposed: Wt[n][k] = B[k0+k][n]; loads coalesced in n
        {
            const int c  = t & 63;
            const int jb = (t >> 6) * 16;
#pragma unroll
            for (int i = 0; i < 16; ++i) {
                const int j = jb + i;
                Wt[swz(c, j)] = Bm[(size_t)(k0 + j) * ldb + c];
            }
        }
        __syncthreads();
#pragma unroll
        for (int j4 = 0; j4 < 64; j4 += 4) {
            float4 xa[4], wb[4];
#pragma unroll
            for (int ii = 0; ii < 4; ++ii) xa[ii] = *(const float4*)&Xs[swz(tr * 4 + ii, j4)];
#pragma unroll
            for (int kk = 0; kk < 4; ++kk) wb[kk] = *(const float4*)&Wt[swz(tc * 4 + kk, j4)];
#pragma unroll
            for (int ii = 0; ii < 4; ++ii)
#pragma unroll
                for (int kk = 0; kk < 4; ++kk)
                    acc[ii][kk] += xa[ii].x * wb[kk].x + xa[ii].y * wb[kk].y +
                                   xa[ii].z * wb[kk].z + xa[ii].w * wb[kk].w;
        }
        __syncthreads();
    }
#pragma unroll
    for (int ii = 0; ii < 4; ++ii) {
        float4 v = make_float4(acc[ii][0], acc[ii][1], acc[ii][2], acc[ii][3]);
        *(float4*)&C[(size_t)(sblk * 64 + tr * 4 + ii) * ldc + tc * 4] = v;
    }
}

// ---------------------------------------------------------------------------
// QKV projection: grid (S/64, H, 3). z selects W_q/W_k/W_v.
// Q/K/V stored [h][s][64].
// ---------------------------------------------------------------------------
__global__ __launch_bounds__(256) void qkv_proj_kernel(
    const float* __restrict__ x,
    const float* __restrict__ Wq, const float* __restrict__ Wk, const float* __restrict__ Wv,
    float* __restrict__ Q, float* __restrict__ K, float* __restrict__ V)
{
    __shared__ float Xs[64 * 64];
    __shared__ float Wt[64 * 64];
    const int sblk  = blockIdx.x;
    const int h     = blockIdx.y;
    const int which = blockIdx.z;
    const float* W = (which == 0) ? Wq : (which == 1) ? Wk : Wv;
    float*       O = (which == 0) ? Q  : (which == 1) ? K  : V;
    gemm_tile(x, W + (size_t)h * DIN * DK, O + (size_t)h * S_LEN * DK,
              DIN, DK, DK, DIN, sblk, Xs, Wt);
}

// ---------------------------------------------------------------------------
// Output projection: out[s][o] = sum_c vals[s][c] * Wo_flat[c][o]
// grid (S/64, DOUT/64)
// ---------------------------------------------------------------------------
__global__ __launch_bounds__(256) void out_proj_kernel(
    const float* __restrict__ vals, const float* __restrict__ Wo, float* __restrict__ out)
{
    __shared__ float Xs[64 * 64];
    __shared__ float Wt[64 * 64];
    const int sblk = blockIdx.x;
    const int ob   = blockIdx.y;
    gemm_tile(vals, Wo + ob * 64, out + ob * 64,
              NH * DV, DOUT, DOUT, NH * DV, sblk, Xs, Wt);
}

// ---------------------------------------------------------------------------
// Flash attention, causal, one block per (64-query tile, head).
// Block 256 threads; thread (tr=t>>4, tc=t&15) owns a 4x4 score/output tile.
// Wave w owns q-rows [16w,16w+16); each row lives in 16 contiguous lanes so
// softmax row max/sum are 4-level __shfl_xor reductions.
// Output written to vals[s][h*64+v] so the output projection is one flat GEMM.
// ---------------------------------------------------------------------------
__global__ __launch_bounds__(256) void attn_kernel(
    const float* __restrict__ Q, const float* __restrict__ K, const float* __restrict__ V,
    float* __restrict__ vals)
{
    __shared__ float Qs[64 * 64];
    __shared__ float Ks[64 * 64];
    __shared__ float Vs[64 * 64];
    __shared__ float Pt[64 * 64];   // P transposed: Pt[k][q]

    const int qb = blockIdx.x;
    const int h  = blockIdx.y;
    const float* Qh = Q + (size_t)h * S_LEN * DK;
    const float* Kh = K + (size_t)h * S_LEN * DK;
    const float* Vh = V + (size_t)h * S_LEN * DV;

    const int t  = threadIdx.x;
    const int tc = t & 15;
    const int tr = t >> 4;

    // stage Q tile once
    {
        const int col4 = (t & 15) << 2;
        const int rowb = t >> 4;
#pragma unroll
        for (int p = 0; p < 4; ++p) {
            const int row = rowb + p * 16;
            *(float4*)&Qs[swz(row, col4)] =
                *(const float4*)&Qh[(size_t)(qb * 64 + row) * DK + col4];
        }
    }

    float m_i[4], l_i[4], o_acc[4][4];
#pragma unroll
    for (int ii = 0; ii < 4; ++ii) {
        m_i[ii] = -1e30f;
        l_i[ii] = 0.f;
#pragma unroll
        for (int kk = 0; kk < 4; ++kk) o_acc[ii][kk] = 0.f;
    }

    for (int kb = 0; kb <= qb; ++kb) {
        __syncthreads();   // previous iteration's Pt/Vs reads done; Qs staged (first iter)
        // stage K and V tiles
        {
            const int col4 = (t & 15) << 2;
            const int rowb = t >> 4;
#pragma unroll
            for (int p = 0; p < 4; ++p) {
                const int row = rowb + p * 16;
                *(float4*)&Ks[swz(row, col4)] =
                    *(const float4*)&Kh[(size_t)(kb * 64 + row) * DK + col4];
                *(float4*)&Vs[swz(row, col4)] =
                    *(const float4*)&Vh[(size_t)(kb * 64 + row) * DV + col4];
            }
        }
        __syncthreads();

        // scores: sc[ii][kk] = Q[4tr+ii] . K[4tc+kk]
        float sc[4][4];
#pragma unroll
        for (int ii = 0; ii < 4; ++ii)
#pragma unroll
            for (int kk = 0; kk < 4; ++kk) sc[ii][kk] = 0.f;
#pragma unroll
        for (int d4 = 0; d4 < 64; d4 += 4) {
            float4 qa[4], kv[4];
#pragma unroll
            for (int ii = 0; ii < 4; ++ii) qa[ii] = *(const float4*)&Qs[swz(tr * 4 + ii, d4)];
#pragma unroll
            for (int kk = 0; kk < 4; ++kk) kv[kk] = *(const float4*)&Ks[swz(tc * 4 + kk, d4)];
#pragma unroll
            for (int ii = 0; ii < 4; ++ii)
#pragma unroll
                for (int kk = 0; kk < 4; ++kk)
                    sc[ii][kk] += qa[ii].x * kv[kk].x + qa[ii].y * kv[kk].y +
                                  qa[ii].z * kv[kk].z + qa[ii].w * kv[kk].w;
        }

        // scale + causal mask (diagonal block only)
        const float scale = 0.125f;   // 1/sqrt(64)
        if (kb == qb) {
#pragma unroll
            for (int ii = 0; ii < 4; ++ii) {
                const int rg = qb * 64 + tr * 4 + ii;
#pragma unroll
                for (int kk = 0; kk < 4; ++kk) {
                    const int cg = kb * 64 + tc * 4 + kk;
                    sc[ii][kk] = (cg > rg) ? -1e30f : sc[ii][kk] * scale;
                }
            }
        } else {
#pragma unroll
            for (int ii = 0; ii < 4; ++ii)
#pragma unroll
                for (int kk = 0; kk < 4; ++kk) sc[ii][kk] *= scale;
        }

        // online softmax update (reductions across the row's 16 lanes)
        float p[4][4];
#pragma unroll
        for (int ii = 0; ii < 4; ++ii) {
            float rowmax = fmaxf(fmaxf(sc[ii][0], sc[ii][1]), fmaxf(sc[ii][2], sc[ii][3]));
#pragma unroll
            for (int off = 8; off >= 1; off >>= 1)
                rowmax = fmaxf(rowmax, __shfl_xor(rowmax, off, 64));
            const float m_new = fmaxf(m_i[ii], rowmax);
            const float alpha = __expf(m_i[ii] - m_new);
            float rowsum = 0.f;
#pragma unroll
            for (int kk = 0; kk < 4; ++kk) {
                p[ii][kk] = __expf(sc[ii][kk] - m_new);
                rowsum += p[ii][kk];
            }
#pragma unroll
            for (int off = 8; off >= 1; off >>= 1)
                rowsum += __shfl_xor(rowsum, off, 64);
            l_i[ii] = l_i[ii] * alpha + rowsum;
            m_i[ii] = m_new;
#pragma unroll
            for (int kk = 0; kk < 4; ++kk) o_acc[ii][kk] *= alpha;
        }

        // write P transposed: Pt[4tc+kk][4tr..4tr+3]
#pragma unroll
        for (int kk = 0; kk < 4; ++kk) {
            float4 v = make_float4(p[0][kk], p[1][kk], p[2][kk], p[3][kk]);
            *(float4*)&Pt[swz(tc * 4 + kk, tr * 4)] = v;
        }
        __syncthreads();

        // PV: outer product over k; V in natural layout
#pragma unroll 8
        for (int k = 0; k < 64; ++k) {
            const float4 pa = *(const float4*)&Pt[swz(k, tr * 4)];
            const float4 vb = *(const float4*)&Vs[swz(k, tc * 4)];
            o_acc[0][0] += pa.x * vb.x; o_acc[0][1] += pa.x * vb.y;
            o_acc[0][2] += pa.x * vb.z; o_acc[0][3] += pa.x * vb.w;
            o_acc[1][0] += pa.y * vb.x; o_acc[1][1] += pa.y * vb.y;
            o_acc[1][2] += pa.y * vb.z; o_acc[1][3] += pa.y * vb.w;
            o_acc[2][0] += pa.z * vb.x; o_acc[2][1] += pa.z * vb.y;
            o_acc[2][2] += pa.z * vb.z; o_acc[2][3] += pa.z * vb.w;
            o_acc[3][0] += pa.w * vb.x; o_acc[3][1] += pa.w * vb.y;
            o_acc[3][2] += pa.w * vb.z; o_acc[3][3] += pa.w * vb.w;
        }
    }

    // epilogue: normalize and store to vals[s][h*64 + v]
#pragma unroll
    for (int ii = 0; ii < 4; ++ii) {
        const float inv = 1.f / l_i[ii];
        float4 v = make_float4(o_acc[ii][0] * inv, o_acc[ii][1] * inv,
                               o_acc[ii][2] * inv, o_acc[ii][3] * inv);
        *(float4*)&vals[(size_t)(qb * 64 + tr * 4 + ii) * (NH * DV) + h * DV + tc * 4] = v;
    }
}

// ---------------------------------------------------------------------------
// Launch: proj -> attention -> out-proj, all on `stream`.
// Workspace: Q (8MB) | K (8MB) | V (8MB) | vals (8MB)  = 32 MB total.
// ---------------------------------------------------------------------------
extern "C" void kernel_launch(void* const* d_in, const int* in_sizes, int n_in,
                              void* d_out, int out_size, void* d_ws, size_t ws_size,
                              hipStream_t stream)
{
    const float* x  = (const float*)d_in[0];
    const float* Wq = (const float*)d_in[1];
    const float* Wk = (const float*)d_in[2];
    const float* Wv = (const float*)d_in[3];
    const float* Wo = (const float*)d_in[4];
    float* out = (float*)d_out;

    float* Q    = (float*)d_ws;
    float* K    = Q + (size_t)NH * S_LEN * DK;
    float* V    = K + (size_t)NH * S_LEN * DK;
    float* vals = V + (size_t)NH * S_LEN * DV;

    qkv_proj_kernel<<<dim3(S_LEN / 64, NH, 3), 256, 0, stream>>>(x, Wq, Wk, Wv, Q, K, V);
    attn_kernel<<<dim3(S_LEN / 64, NH), 256, 0, stream>>>(Q, K, V, vals);
    out_proj_kernel<<<dim3(S_LEN / 64, DOUT / 64), 256, 0, stream>>>(vals, Wo, out);
}

// Round 2
// 243.003 us; speedup vs baseline: 7.2404x; 7.2404x over previous
//
#include <hip/hip_runtime.h>
#include <math.h>

#define S_LEN 4096
#define DIN   512
#define NH    8
#define DK    64
#define DV    64
#define DOUT  512

typedef __attribute__((ext_vector_type(8))) short bf16x8;
typedef __attribute__((ext_vector_type(4))) short bf16x4;
typedef __attribute__((ext_vector_type(4))) float f32x4;

// fp32 -> bf16 round-to-nearest-even (inputs are finite, no NaN handling needed)
__device__ __forceinline__ short f2bf(float f) {
    union { float f; unsigned u; } v; v.f = f;
    unsigned r = v.u + 0x7fffu + ((v.u >> 16) & 1u);
    return (short)(r >> 16);
}

// ---------------------------------------------------------------------------
// Prep: x -> bf16 (xb [4096][512]); weights -> bf16 TRANSPOSED so the GEMM
// B-operand LDS tiles are [n][k] with contiguous k (what the MFMA B-fragment
// wants):  Wqkvt[g=which*8+h][n=0..63][k=0..511],  Wot[n=0..511][k=c=h*64+v].
// ---------------------------------------------------------------------------
#define X_CHUNKS   524288            // 4096*512/4
#define WQKV_ELEMS 786432            // 24*64*512
#define WO_ELEMS   262144            // 512*512
#define PREP_TOTAL (X_CHUNKS + WQKV_ELEMS + WO_ELEMS)   // 1,572,864 = 6144*256

__global__ __launch_bounds__(256) void prep_kernel(
    const float* __restrict__ x,
    const float* __restrict__ Wq, const float* __restrict__ Wk,
    const float* __restrict__ Wv, const float* __restrict__ Wo,
    short* __restrict__ xb, short* __restrict__ Wqkvt, short* __restrict__ Wot)
{
    const int id = blockIdx.x * 256 + threadIdx.x;
    if (id < X_CHUNKS) {
        const float4 v = *(const float4*)&x[(size_t)id * 4];
        bf16x4 o; o[0] = f2bf(v.x); o[1] = f2bf(v.y); o[2] = f2bf(v.z); o[3] = f2bf(v.w);
        *(bf16x4*)&xb[(size_t)id * 4] = o;
    } else if (id < X_CHUNKS + WQKV_ELEMS) {
        const int j = id - X_CHUNKS;
        const int k = j & 511, n = (j >> 9) & 63, g = j >> 15;
        const int which = g >> 3, h = g & 7;
        const float* W = (which == 0) ? Wq : (which == 1) ? Wk : Wv;
        Wqkvt[((size_t)g * 64 + n) * 512 + k] = f2bf(W[((size_t)h * 512 + k) * 64 + n]);
    } else {
        const int j = id - (X_CHUNKS + WQKV_ELEMS);
        const int c = j & 511, n = j >> 9;       // c = h*64+v
        const int h = c >> 6, vv = c & 63;
        Wot[(size_t)n * 512 + c] = f2bf(Wo[((size_t)h * 64 + vv) * 512 + n]);
    }
}

// ---------------------------------------------------------------------------
// 64x64-tile MFMA GEMM mainloop (K=512). Block = 256 thr = 4 waves.
// Wave w computes C rows 16w..16w+15 x all 64 cols as 4 16x16 MFMA tiles.
// A LDS [m][k] (stride 72 bf16 = 144B: frag reads are 2-way-free on banks),
// B LDS [n][k] (same).  acc[nt] C-layout: col=lane&15, row=quad*4+r.
// ---------------------------------------------------------------------------
__device__ __forceinline__ void gemm_mainloop_512(
    const short* __restrict__ Arow, const short* __restrict__ Brow,
    short* As, short* Bs, f32x4 acc[4])
{
    const int t = threadIdx.x;
    const int wave = t >> 6, lane = t & 63, n16 = lane & 15, quad = lane >> 4;
    const int r4 = t >> 2, c16 = (t & 3) * 16;
    for (int k0 = 0; k0 < 512; k0 += 64) {
        __syncthreads();   // previous iteration's fragment reads complete
        *(bf16x8*)&As[r4 * 72 + c16]     = *(const bf16x8*)&Arow[(size_t)r4 * 512 + k0 + c16];
        *(bf16x8*)&As[r4 * 72 + c16 + 8] = *(const bf16x8*)&Arow[(size_t)r4 * 512 + k0 + c16 + 8];
        *(bf16x8*)&Bs[r4 * 72 + c16]     = *(const bf16x8*)&Brow[(size_t)r4 * 512 + k0 + c16];
        *(bf16x8*)&Bs[r4 * 72 + c16 + 8] = *(const bf16x8*)&Brow[(size_t)r4 * 512 + k0 + c16 + 8];
        __syncthreads();
#pragma unroll
        for (int kh = 0; kh < 2; ++kh) {
            const bf16x8 a = *(const bf16x8*)&As[(wave * 16 + n16) * 72 + kh * 32 + quad * 8];
#pragma unroll
            for (int nt = 0; nt < 4; ++nt) {
                const bf16x8 b = *(const bf16x8*)&Bs[(nt * 16 + n16) * 72 + kh * 32 + quad * 8];
                acc[nt] = __builtin_amdgcn_mfma_f32_16x16x32_bf16(a, b, acc[nt], 0, 0, 0);
            }
        }
    }
}

// QKV projection: grid (64 sblk, 24 g).  g -> which (0=Q,1=K,2=V), head.
// Q,K written [h][s][64] bf16.  V written TRANSPOSED [h][d][s] bf16 via LDS
// bounce so attention can stage V^T tiles with contiguous 16B reads.
__global__ __launch_bounds__(256) void qkv_gemm_kernel(
    const short* __restrict__ xb, const short* __restrict__ Wqkvt,
    short* __restrict__ Qg, short* __restrict__ Kg, short* __restrict__ Vtg)
{
    __shared__ short As[64 * 72];
    __shared__ short Bs[64 * 72];
    const int sblk = blockIdx.x, g = blockIdx.y;
    const int which = g >> 3, h = g & 7;
    const int t = threadIdx.x;
    const int wave = t >> 6, lane = t & 63, n16 = lane & 15, quad = lane >> 4;

    f32x4 acc[4] = {{0,0,0,0},{0,0,0,0},{0,0,0,0},{0,0,0,0}};
    gemm_mainloop_512(xb + (size_t)sblk * 64 * 512, Wqkvt + (size_t)g * 64 * 512, As, Bs, acc);

    if (which < 2) {
        short* O = ((which == 0) ? Qg : Kg) + (size_t)h * S_LEN * 64;
#pragma unroll
        for (int nt = 0; nt < 4; ++nt)
#pragma unroll
            for (int r = 0; r < 4; ++r) {
                const int s = sblk * 64 + wave * 16 + quad * 4 + r;
                O[(size_t)s * 64 + nt * 16 + n16] = f2bf(acc[nt][r]);
            }
    } else {
        __syncthreads();                    // done with As fragment reads
        // transpose tile into As: As[d][s_local], stride 72
#pragma unroll
        for (int nt = 0; nt < 4; ++nt)
#pragma unroll
            for (int r = 0; r < 4; ++r)
                As[(nt * 16 + n16) * 72 + wave * 16 + quad * 4 + r] = f2bf(acc[nt][r]);
        __syncthreads();
        short* O = Vtg + (size_t)h * 64 * S_LEN + sblk * 64;
        const int r4 = t >> 2, c16 = (t & 3) * 16;
        *(bf16x8*)&O[(size_t)r4 * S_LEN + c16]     = *(const bf16x8*)&As[r4 * 72 + c16];
        *(bf16x8*)&O[(size_t)r4 * S_LEN + c16 + 8] = *(const bf16x8*)&As[r4 * 72 + c16 + 8];
    }
}

// Output projection: vals bf16 [4096][512] x Wot -> out fp32 [4096][512].
__global__ __launch_bounds__(256) void out_gemm_kernel(
    const short* __restrict__ vals, const short* __restrict__ Wot, float* __restrict__ out)
{
    __shared__ short As[64 * 72];
    __shared__ short Bs[64 * 72];
    const int sblk = blockIdx.x, g = blockIdx.y;   // g = output 64-col block
    const int t = threadIdx.x;
    const int wave = t >> 6, lane = t & 63, n16 = lane & 15, quad = lane >> 4;

    f32x4 acc[4] = {{0,0,0,0},{0,0,0,0},{0,0,0,0},{0,0,0,0}};
    gemm_mainloop_512(vals + (size_t)sblk * 64 * 512, Wot + (size_t)g * 64 * 512, As, Bs, acc);

#pragma unroll
    for (int nt = 0; nt < 4; ++nt)
#pragma unroll
        for (int r = 0; r < 4; ++r) {
            const int s = sblk * 64 + wave * 16 + quad * 4 + r;
            out[(size_t)s * DOUT + g * 64 + nt * 16 + n16] = acc[nt][r];
        }
}

// ---------------------------------------------------------------------------
// Flash attention, causal, bf16 MFMA. One block per (64-q tile, head).
// QK^T: A=Q[m=q][k=d], B=K[key][d] staged [key][d] (B-frag contiguous in d).
// PV:   A=P[m=q][k=key] via swizzled LDS, B=V staged transposed [d][key].
// Ps swizzle: elem (q,key) at q*64 + (key ^ ((q&7)<<3)) — keeps A-frag 16B
// reads contiguous while spreading write banks.
// ---------------------------------------------------------------------------
__global__ __launch_bounds__(256) void attn_kernel(
    const short* __restrict__ Qg, const short* __restrict__ Kg,
    const short* __restrict__ Vtg, short* __restrict__ vals)
{
    __shared__ short Qs[64 * 72];
    __shared__ short Ks[64 * 72];
    __shared__ short Vts[64 * 72];   // [d][key]
    __shared__ short Ps[64 * 64];    // swizzled

    // causal load-balance: pair qb with 63-qb across the two grid halves
    const int qb = (blockIdx.y & 4) ? (63 - (int)blockIdx.x) : (int)blockIdx.x;
    const int h  = blockIdx.y;
    const short* Qh  = Qg  + (size_t)h * S_LEN * 64;
    const short* Kh  = Kg  + (size_t)h * S_LEN * 64;
    const short* Vth = Vtg + (size_t)h * 64 * S_LEN;

    const int t = threadIdx.x;
    const int wave = t >> 6, lane = t & 63, n16 = lane & 15, quad = lane >> 4;
    const int r4 = t >> 2, c16 = (t & 3) * 16;

    // stage Q tile once; hoist the (loop-invariant) A-fragments into regs
    *(bf16x8*)&Qs[r4 * 72 + c16]     = *(const bf16x8*)&Qh[(size_t)(qb * 64 + r4) * 64 + c16];
    *(bf16x8*)&Qs[r4 * 72 + c16 + 8] = *(const bf16x8*)&Qh[(size_t)(qb * 64 + r4) * 64 + c16 + 8];
    __syncthreads();
    bf16x8 aq[2];
#pragma unroll
    for (int kh = 0; kh < 2; ++kh)
        aq[kh] = *(const bf16x8*)&Qs[(wave * 16 + n16) * 72 + kh * 32 + quad * 8];

    float m_i[4] = {-1e30f, -1e30f, -1e30f, -1e30f};
    float l_i[4] = {0.f, 0.f, 0.f, 0.f};
    f32x4 oacc[4] = {{0,0,0,0},{0,0,0,0},{0,0,0,0},{0,0,0,0}};

    const int q_loc = wave * 16 + quad * 4;    // this lane's first owned q row (local)

    for (int kb = 0; kb <= qb; ++kb) {
        __syncthreads();   // prior iteration's Ks/Vts/Ps reads complete
        *(bf16x8*)&Ks[r4 * 72 + c16]      = *(const bf16x8*)&Kh[(size_t)(kb * 64 + r4) * 64 + c16];
        *(bf16x8*)&Ks[r4 * 72 + c16 + 8]  = *(const bf16x8*)&Kh[(size_t)(kb * 64 + r4) * 64 + c16 + 8];
        *(bf16x8*)&Vts[r4 * 72 + c16]     = *(const bf16x8*)&Vth[(size_t)r4 * S_LEN + kb * 64 + c16];
        *(bf16x8*)&Vts[r4 * 72 + c16 + 8] = *(const bf16x8*)&Vth[(size_t)r4 * S_LEN + kb * 64 + c16 + 8];
        __syncthreads();

        // QK^T
        f32x4 sc[4] = {{0,0,0,0},{0,0,0,0},{0,0,0,0},{0,0,0,0}};
#pragma unroll
        for (int kh = 0; kh < 2; ++kh) {
#pragma unroll
            for (int nt = 0; nt < 4; ++nt) {
                const bf16x8 b = *(const bf16x8*)&Ks[(nt * 16 + n16) * 72 + kh * 32 + quad * 8];
                sc[nt] = __builtin_amdgcn_mfma_f32_16x16x32_bf16(aq[kh], b, sc[nt], 0, 0, 0);
            }
        }

        // scale + causal mask (diagonal block only)
        if (kb == qb) {
#pragma unroll
            for (int nt = 0; nt < 4; ++nt) {
                const int key_loc = nt * 16 + n16;
#pragma unroll
                for (int r = 0; r < 4; ++r)
                    sc[nt][r] = (key_loc > q_loc + r) ? -1e30f : sc[nt][r] * 0.125f;
            }
        } else {
#pragma unroll
            for (int nt = 0; nt < 4; ++nt)
#pragma unroll
                for (int r = 0; r < 4; ++r) sc[nt][r] *= 0.125f;
        }

        // online softmax per owned row r; write P (bf16) to swizzled LDS
#pragma unroll
        for (int r = 0; r < 4; ++r) {
            float mx = fmaxf(fmaxf(sc[0][r], sc[1][r]), fmaxf(sc[2][r], sc[3][r]));
            mx = fmaxf(mx, __shfl_xor(mx, 1));
            mx = fmaxf(mx, __shfl_xor(mx, 2));
            mx = fmaxf(mx, __shfl_xor(mx, 4));
            mx = fmaxf(mx, __shfl_xor(mx, 8));
            const float mnew  = fmaxf(m_i[r], mx);
            const float alpha = __expf(m_i[r] - mnew);
            float p[4], rs = 0.f;
#pragma unroll
            for (int nt = 0; nt < 4; ++nt) { p[nt] = __expf(sc[nt][r] - mnew); rs += p[nt]; }
            rs += __shfl_xor(rs, 1);
            rs += __shfl_xor(rs, 2);
            rs += __shfl_xor(rs, 4);
            rs += __shfl_xor(rs, 8);
            l_i[r] = l_i[r] * alpha + rs;
            m_i[r] = mnew;
            const int q = q_loc + r;
            const int sw = (q & 7) << 3;
#pragma unroll
            for (int nt = 0; nt < 4; ++nt) {
                oacc[nt][r] *= alpha;
                Ps[q * 64 + ((nt * 16 + n16) ^ sw)] = f2bf(p[nt]);
            }
        }
        __syncthreads();   // Ps visible to all waves

        // PV: O += P x V
#pragma unroll
        for (int kh = 0; kh < 2; ++kh) {
            const int m = wave * 16 + n16;
            const bf16x8 a = *(const bf16x8*)&Ps[m * 64 + ((kh * 32 + quad * 8) ^ ((m & 7) << 3))];
#pragma unroll
            for (int nt = 0; nt < 4; ++nt) {
                const bf16x8 b = *(const bf16x8*)&Vts[(nt * 16 + n16) * 72 + kh * 32 + quad * 8];
                oacc[nt] = __builtin_amdgcn_mfma_f32_16x16x32_bf16(a, b, oacc[nt], 0, 0, 0);
            }
        }
    }

    // epilogue: normalize, write vals[s][h*64+d] bf16
#pragma unroll
    for (int r = 0; r < 4; ++r) {
        const float inv = 1.f / l_i[r];
        const int s = qb * 64 + q_loc + r;
#pragma unroll
        for (int nt = 0; nt < 4; ++nt)
            vals[(size_t)s * (NH * DV) + h * DV + nt * 16 + n16] = f2bf(oacc[nt][r] * inv);
    }
}

// ---------------------------------------------------------------------------
// Workspace (bf16 shorts): xb 4MB | Wqkvt 1.5MB | Wot 0.5MB | Q 4MB | K 4MB |
// Vt 4MB | vals 4MB  = 22MB total.
// ---------------------------------------------------------------------------
extern "C" void kernel_launch(void* const* d_in, const int* in_sizes, int n_in,
                              void* d_out, int out_size, void* d_ws, size_t ws_size,
                              hipStream_t stream)
{
    const float* x  = (const float*)d_in[0];
    const float* Wq = (const float*)d_in[1];
    const float* Wk = (const float*)d_in[2];
    const float* Wv = (const float*)d_in[3];
    const float* Wo = (const float*)d_in[4];
    float* out = (float*)d_out;

    short* xb    = (short*)d_ws;
    short* Wqkvt = xb + 2097152;
    short* Wot   = Wqkvt + 786432;
    short* Qg    = Wot + 262144;
    short* Kg    = Qg + 2097152;
    short* Vtg   = Kg + 2097152;
    short* vals  = Vtg + 2097152;

    prep_kernel<<<PREP_TOTAL / 256, 256, 0, stream>>>(x, Wq, Wk, Wv, Wo, xb, Wqkvt, Wot);
    qkv_gemm_kernel<<<dim3(S_LEN / 64, 24), 256, 0, stream>>>(xb, Wqkvt, Qg, Kg, Vtg);
    attn_kernel<<<dim3(S_LEN / 64, NH), 256, 0, stream>>>(Qg, Kg, Vtg, vals);
    out_gemm_kernel<<<dim3(S_LEN / 64, DOUT / 64), 256, 0, stream>>>(vals, Wot, out);
}

// Round 3
// 164.382 us; speedup vs baseline: 10.7033x; 1.4783x over previous
//
#include <hip/hip_runtime.h>
#include <math.h>

#define S_LEN 4096
#define NH    8

typedef __attribute__((ext_vector_type(8))) short bf16x8;
typedef __attribute__((ext_vector_type(4))) short bf16x4;
typedef __attribute__((ext_vector_type(4))) float f32x4;

#define QSCALE 0.18033688011112042f   // 0.125 * log2(e): scores land in exp2 domain

// fp32 -> bf16 round-to-nearest-even
__device__ __forceinline__ short f2bf(float f) {
    union { float f; unsigned u; } v; v.f = f;
    unsigned r = v.u + 0x7fffu + ((v.u >> 16) & 1u);
    return (short)(r >> 16);
}

// async 16B global->LDS; HW writes lane i's 16B to ldsbase + i*16
__device__ __forceinline__ void gload16(const void* g, void* l) {
    __builtin_amdgcn_global_load_lds(
        (const __attribute__((address_space(1))) unsigned*)g,
        (__attribute__((address_space(3))) unsigned*)l, 16, 0, 0);
}

// ---------------------------------------------------------------------------
// Stage a 64x64 bf16 tile (global row stride = gstride shorts) into an 8KB
// LDS tile with XOR-swizzled 16B column groups:
//   phys(row, cg) = row*128B + ((cg ^ (row&7)) * 16B)
// The swizzle is applied on the GLOBAL source address (per-lane), so the
// wave-uniform-base global_load_lds lands data exactly where frag() expects.
// Fragment reads at fixed cg across 16 rows then hit 8 bank groups 2-way
// (free, m136). Global side stays fully coalesced (permutation within 128B).
// ---------------------------------------------------------------------------
__device__ __forceinline__ void stage_tile(const short* gsrc, size_t gstride,
                                           short* tile, int t)
{
    const int wave = t >> 6, lane = t & 63;
    const int sub = lane >> 3;            // row within this 8-row chunk
    const int cg  = (lane & 7) ^ sub;     // swizzled source column group
#pragma unroll
    for (int j = 0; j < 2; ++j) {
        const int chunk = wave * 2 + j;   // 8 chunks of 8 rows per tile
        const int row = chunk * 8 + sub;
        gload16(gsrc + (size_t)row * gstride + cg * 8, tile + chunk * 512);
    }
}

// 16B fragment read honoring the stage_tile swizzle
__device__ __forceinline__ bf16x8 frag(const short* tile, int row, int cg) {
    return *(const bf16x8*)&tile[row * 64 + ((cg ^ (row & 7)) << 3)];
}

// ---------------------------------------------------------------------------
// 64x64-tile MFMA GEMM mainloop, K=512, double-buffered global_load_lds.
// C[s_loc = wave*16 + quad*4 + r][n = nt*16 + n16].
// ---------------------------------------------------------------------------
__device__ __forceinline__ void gemm_mainloop_512(
    const short* __restrict__ Arow, const short* __restrict__ Brow,
    short* As, short* Bs, f32x4 acc[4], int t)
{
    const int wave = t >> 6, lane = t & 63, n16 = lane & 15, quad = lane >> 4;
    stage_tile(Arow, 512, As, t);
    stage_tile(Brow, 512, Bs, t);
    __syncthreads();
    for (int c = 0; c < 8; ++c) {
        const int cur = c & 1;
        if (c < 7) {   // async prefetch; end-of-iter barrier drains it
            stage_tile(Arow + (c + 1) * 64, 512, As + (1 - cur) * 4096, t);
            stage_tile(Brow + (c + 1) * 64, 512, Bs + (1 - cur) * 4096, t);
        }
        const short* as = As + cur * 4096;
        const short* bs = Bs + cur * 4096;
#pragma unroll
        for (int kh = 0; kh < 2; ++kh) {
            const bf16x8 a = frag(as, wave * 16 + n16, kh * 4 + quad);
#pragma unroll
            for (int nt = 0; nt < 4; ++nt) {
                const bf16x8 b = frag(bs, nt * 16 + n16, kh * 4 + quad);
                acc[nt] = __builtin_amdgcn_mfma_f32_16x16x32_bf16(a, b, acc[nt], 0, 0, 0);
            }
        }
        __syncthreads();
    }
}

// ---------------------------------------------------------------------------
// Prep: x->bf16; weight transposes via coalesced LDS tiles.
//   Wqkvt[g=which*8+h][n][k=0..511] = W_which[h][k][n]
//   Wot[n][c=h*64+v]               = Wo[h][v][n]
// grid: [0,1024) x-convert | [1024,1216) Wqkv tiles | [1216,1280) Wo tiles
// ---------------------------------------------------------------------------
__global__ __launch_bounds__(256) void prep_kernel(
    const float* __restrict__ x,
    const float* __restrict__ Wq, const float* __restrict__ Wk,
    const float* __restrict__ Wv, const float* __restrict__ Wo,
    short* __restrict__ xb, short* __restrict__ Wqkvt, short* __restrict__ Wot)
{
    __shared__ short T[64 * 66];
    const int b = blockIdx.x, t = threadIdx.x;
    if (b < 1024) {                        // x conversion, 2048 elems/block
        const size_t idx = (size_t)b * 2048 + t * 8;
        const float4 a = *(const float4*)&x[idx];
        const float4 c = *(const float4*)&x[idx + 4];
        bf16x8 o;
        o[0] = f2bf(a.x); o[1] = f2bf(a.y); o[2] = f2bf(a.z); o[3] = f2bf(a.w);
        o[4] = f2bf(c.x); o[5] = f2bf(c.y); o[6] = f2bf(c.z); o[7] = f2bf(c.w);
        *(bf16x8*)&xb[idx] = o;
        return;
    }
    const int c4 = (t & 15) * 4, rsub = t >> 4;
    const int orow = t >> 2, oc16 = (t & 3) * 16;
    if (b < 1216) {                        // Wq/Wk/Wv transpose
        const int jj = b - 1024, g = jj >> 3, kb = jj & 7;
        const int which = g >> 3, h = g & 7;
        const float* W = ((which == 0) ? Wq : (which == 1) ? Wk : Wv) + (size_t)h * 512 * 64;
#pragma unroll
        for (int p = 0; p < 4; ++p) {
            const int row = p * 16 + rsub;                       // k within tile
            const float4 v = *(const float4*)&W[(size_t)(kb * 64 + row) * 64 + c4];
            T[(c4 + 0) * 66 + row] = f2bf(v.x);
            T[(c4 + 1) * 66 + row] = f2bf(v.y);
            T[(c4 + 2) * 66 + row] = f2bf(v.z);
            T[(c4 + 3) * 66 + row] = f2bf(v.w);
        }
        __syncthreads();
        short* O = &Wqkvt[((size_t)g * 64 + orow) * 512 + kb * 64];
        *(bf16x8*)&O[oc16]     = *(const bf16x8*)&T[orow * 66 + oc16];
        *(bf16x8*)&O[oc16 + 8] = *(const bf16x8*)&T[orow * 66 + oc16 + 8];
    } else {                               // Wo transpose
        const int jj = b - 1216, h = jj >> 3, nb = jj & 7;
        const float* W = Wo + (size_t)h * 64 * 512;
#pragma unroll
        for (int p = 0; p < 4; ++p) {
            const int row = p * 16 + rsub;                       // v within tile
            const float4 v = *(const float4*)&W[(size_t)row * 512 + nb * 64 + c4];
            T[(c4 + 0) * 66 + row] = f2bf(v.x);
            T[(c4 + 1) * 66 + row] = f2bf(v.y);
            T[(c4 + 2) * 66 + row] = f2bf(v.z);
            T[(c4 + 3) * 66 + row] = f2bf(v.w);
        }
        __syncthreads();
        short* O = &Wot[((size_t)nb * 64 + orow) * 512 + h * 64];
        *(bf16x8*)&O[oc16]     = *(const bf16x8*)&T[orow * 66 + oc16];
        *(bf16x8*)&O[oc16 + 8] = *(const bf16x8*)&T[orow * 66 + oc16 + 8];
    }
}

// ---------------------------------------------------------------------------
// QKV projection. grid (64 sblk, 24 g). Q pre-scaled by QSCALE; Q,K stored
// [h][s][64]; V stored transposed [h][d][s] via LDS bounce.
// ---------------------------------------------------------------------------
__global__ __launch_bounds__(256) void qkv_gemm_kernel(
    const short* __restrict__ xb, const short* __restrict__ Wqkvt,
    short* __restrict__ Qg, short* __restrict__ Kg, short* __restrict__ Vtg)
{
    __shared__ short smem[16384];          // As[2][4096] | Bs[2][4096]
    short* As = smem;
    short* Bs = smem + 8192;
    const int sblk = blockIdx.x, g = blockIdx.y;
    const int which = g >> 3, h = g & 7;
    const int t = threadIdx.x;
    const int wave = t >> 6, lane = t & 63, n16 = lane & 15, quad = lane >> 4;

    f32x4 acc[4] = {{0,0,0,0},{0,0,0,0},{0,0,0,0},{0,0,0,0}};
    gemm_mainloop_512(xb + (size_t)sblk * 64 * 512, Wqkvt + (size_t)g * 64 * 512,
                      As, Bs, acc, t);

    if (which < 2) {
        const float scale = (which == 0) ? QSCALE : 1.0f;
        short* O = ((which == 0) ? Qg : Kg) + (size_t)h * S_LEN * 64;
#pragma unroll
        for (int nt = 0; nt < 4; ++nt)
#pragma unroll
            for (int r = 0; r < 4; ++r) {
                const int s = sblk * 64 + wave * 16 + quad * 4 + r;
                O[(size_t)s * 64 + nt * 16 + n16] = f2bf(acc[nt][r] * scale);
            }
    } else {
        __syncthreads();                   // staging reads done; reuse smem
        short* Tr = smem;                  // Tr[d][s_loc], stride 66
#pragma unroll
        for (int nt = 0; nt < 4; ++nt)
#pragma unroll
            for (int r = 0; r < 4; ++r)
                Tr[(nt * 16 + n16) * 66 + wave * 16 + quad * 4 + r] = f2bf(acc[nt][r]);
        __syncthreads();
        short* O = Vtg + (size_t)h * 64 * S_LEN + sblk * 64;
        const int r4 = t >> 2, c16 = (t & 3) * 16;
        *(bf16x8*)&O[(size_t)r4 * S_LEN + c16]     = *(const bf16x8*)&Tr[r4 * 66 + c16];
        *(bf16x8*)&O[(size_t)r4 * S_LEN + c16 + 8] = *(const bf16x8*)&Tr[r4 * 66 + c16 + 8];
    }
}

// ---------------------------------------------------------------------------
// Output projection: vals bf16 [4096][512] x Wot[n][c] -> out fp32.
// ---------------------------------------------------------------------------
__global__ __launch_bounds__(256) void out_gemm_kernel(
    const short* __restrict__ vals, const short* __restrict__ Wot, float* __restrict__ out)
{
    __shared__ short smem[16384];
    short* As = smem;
    short* Bs = smem + 8192;
    const int sblk = blockIdx.x, g = blockIdx.y;
    const int t = threadIdx.x;
    const int wave = t >> 6, lane = t & 63, n16 = lane & 15, quad = lane >> 4;

    f32x4 acc[4] = {{0,0,0,0},{0,0,0,0},{0,0,0,0},{0,0,0,0}};
    gemm_mainloop_512(vals + (size_t)sblk * 64 * 512, Wot + (size_t)g * 64 * 512,
                      As, Bs, acc, t);

#pragma unroll
    for (int nt = 0; nt < 4; ++nt)
#pragma unroll
        for (int r = 0; r < 4; ++r) {
            const int s = sblk * 64 + wave * 16 + quad * 4 + r;
            out[(size_t)s * 512 + g * 64 + nt * 16 + n16] = acc[nt][r];
        }
}

// ---------------------------------------------------------------------------
// Flash attention, causal, transposed-MFMA formulation.
//  Sc^T[key][q] = K x Q^T  (A=K frag, B=Q frag)  -> lane owns 1 q, 16 keys
//  O^T[v][q]   += V^T x P  (A=V^T frag, B=P frag) -> lane owns 1 q, 16 v
// Softmax state (m,l) is lane-local (replicated x4 quads); reductions are
// in-thread + 2 shuffles. Ps is wave-local -> no barrier between softmax and
// PV; one __syncthreads per k-step (K/V double-buffer swap + vmcnt drain).
// Grid: flat 512; h = id&7 pins each head to one XCD (K/V fits its 4MB L2);
// qb pairing j<32?j:95-j puts qb and 63-qb on the same CU (65 steps each).
// ---------------------------------------------------------------------------
__global__ __launch_bounds__(256) void attn_kernel(
    const short* __restrict__ Qg, const short* __restrict__ Kg,
    const short* __restrict__ Vtg, short* __restrict__ vals)
{
    __shared__ short Ks[2][4096];
    __shared__ short Vs[2][4096];
    __shared__ short Ps[4096];             // [q][key^sw], row stride 64

    const int id = blockIdx.x;
    const int h  = id & 7;
    const int j  = id >> 3;
    const int qb = (j < 32) ? j : 95 - j;

    const short* Kh  = Kg  + (size_t)h * S_LEN * 64;
    const short* Vth = Vtg + (size_t)h * 64 * S_LEN;

    const int t = threadIdx.x;
    const int wave = t >> 6, lane = t & 63, n16 = lane & 15, quad = lane >> 4;
    const int qrow = wave * 16 + n16;      // this lane's q (block-local)
    const int sw   = (qrow & 7) << 3;      // Ps key-index swizzle (8-aligned)

    // Q B-fragments, loop-invariant, direct from global (one-time 16B/lane)
    const short* Qr = Qg + (size_t)h * S_LEN * 64 + (size_t)(qb * 64 + qrow) * 64;
    const bf16x8 bq0 = *(const bf16x8*)&Qr[quad * 8];
    const bf16x8 bq1 = *(const bf16x8*)&Qr[32 + quad * 8];

    float m_i = -1e30f, l_i = 0.f;
    f32x4 oacc[4] = {{0,0,0,0},{0,0,0,0},{0,0,0,0},{0,0,0,0}};

    stage_tile(Kh, 64, Ks[0], t);
    stage_tile(Vth, S_LEN, Vs[0], t);
    __syncthreads();

    for (int kb = 0; kb <= qb; ++kb) {
        const int cur = kb & 1;
        if (kb < qb) {                     // async prefetch into other buffer
            stage_tile(Kh + (size_t)(kb + 1) * 64 * 64, 64, Ks[1 - cur], t);
            stage_tile(Vth + (kb + 1) * 64, S_LEN, Vs[1 - cur], t);
        }

        // Sc^T = K x Q^T
        f32x4 sc[4] = {{0,0,0,0},{0,0,0,0},{0,0,0,0},{0,0,0,0}};
#pragma unroll
        for (int kh = 0; kh < 2; ++kh) {
            const bf16x8 bq = kh ? bq1 : bq0;
#pragma unroll
            for (int mt = 0; mt < 4; ++mt) {
                const bf16x8 a = frag(Ks[cur], mt * 16 + n16, kh * 4 + quad);
                sc[mt] = __builtin_amdgcn_mfma_f32_16x16x32_bf16(a, bq, sc[mt], 0, 0, 0);
            }
        }

        if (kb == qb) {                    // causal mask, diagonal block only
#pragma unroll
            for (int mt = 0; mt < 4; ++mt) {
                const int key0 = mt * 16 + quad * 4;   // C-layout row = quad*4+r
#pragma unroll
                for (int r = 0; r < 4; ++r)
                    if (key0 + r > qrow) sc[mt][r] = -1e30f;
            }
        }

        // online softmax in exp2 domain (QSCALE folded into Q)
        float mx = sc[0][0];
#pragma unroll
        for (int mt = 0; mt < 4; ++mt)
#pragma unroll
            for (int r = 0; r < 4; ++r) mx = fmaxf(mx, sc[mt][r]);
        mx = fmaxf(mx, __shfl_xor(mx, 16));
        mx = fmaxf(mx, __shfl_xor(mx, 32));
        const float mnew  = fmaxf(m_i, mx);
        const float alpha = __builtin_amdgcn_exp2f(m_i - mnew);
        float rs = 0.f;
#pragma unroll
        for (int mt = 0; mt < 4; ++mt) {
            bf16x4 pk;
#pragma unroll
            for (int r = 0; r < 4; ++r) {
                const float p = __builtin_amdgcn_exp2f(sc[mt][r] - mnew);
                rs += p;
                pk[r] = f2bf(p);
            }
            *(bf16x4*)&Ps[qrow * 64 + ((mt * 16 + quad * 4) ^ sw)] = pk;
        }
        rs += __shfl_xor(rs, 16);
        rs += __shfl_xor(rs, 32);
        l_i = l_i * alpha + rs;
        m_i = mnew;
#pragma unroll
        for (int mt = 0; mt < 4; ++mt) {
            oacc[mt][0] *= alpha; oacc[mt][1] *= alpha;
            oacc[mt][2] *= alpha; oacc[mt][3] *= alpha;
        }
        __builtin_amdgcn_wave_barrier();   // Ps writes stay above PV reads

        // O^T += V^T x P (Ps rows are wave-local: no block barrier needed)
#pragma unroll
        for (int kh = 0; kh < 2; ++kh) {
            const bf16x8 bp = *(const bf16x8*)&Ps[qrow * 64 + ((kh * 32 + quad * 8) ^ sw)];
#pragma unroll
            for (int mt = 0; mt < 4; ++mt) {
                const bf16x8 a = frag(Vs[cur], mt * 16 + n16, kh * 4 + quad);
                oacc[mt] = __builtin_amdgcn_mfma_f32_16x16x32_bf16(a, bp, oacc[mt], 0, 0, 0);
            }
        }
        __builtin_amdgcn_wave_barrier();
        __syncthreads();                   // buffer swap + prefetch drain
    }

    // epilogue: normalize, write vals[s][h*64+v] (lane's q fixed = qrow)
    const float inv = 1.f / l_i;
    const int sg = qb * 64 + qrow;
#pragma unroll
    for (int mt = 0; mt < 4; ++mt) {
        bf16x4 pk;
#pragma unroll
        for (int r = 0; r < 4; ++r) pk[r] = f2bf(oacc[mt][r] * inv);
        *(bf16x4*)&vals[(size_t)sg * 512 + h * 64 + mt * 16 + quad * 4] = pk;
    }
}

// ---------------------------------------------------------------------------
// Workspace (shorts): xb 2M | Wqkvt 768K | Wot 256K | Qg 2M | Kg 2M | Vtg 2M |
// vals 2M  ~= 19 MB.
// ---------------------------------------------------------------------------
extern "C" void kernel_launch(void* const* d_in, const int* in_sizes, int n_in,
                              void* d_out, int out_size, void* d_ws, size_t ws_size,
                              hipStream_t stream)
{
    const float* x  = (const float*)d_in[0];
    const float* Wq = (const float*)d_in[1];
    const float* Wk = (const float*)d_in[2];
    const float* Wv = (const float*)d_in[3];
    const float* Wo = (const float*)d_in[4];
    float* out = (float*)d_out;

    short* xb    = (short*)d_ws;
    short* Wqkvt = xb + 2097152;
    short* Wot   = Wqkvt + 786432;
    short* Qg    = Wot + 262144;
    short* Kg    = Qg + 2097152;
    short* Vtg   = Kg + 2097152;
    short* vals  = Vtg + 2097152;

    prep_kernel<<<1280, 256, 0, stream>>>(x, Wq, Wk, Wv, Wo, xb, Wqkvt, Wot);
    qkv_gemm_kernel<<<dim3(64, 24), 256, 0, stream>>>(xb, Wqkvt, Qg, Kg, Vtg);
    attn_kernel<<<512, 256, 0, stream>>>(Qg, Kg, Vtg, vals);
    out_gemm_kernel<<<dim3(64, 8), 256, 0, stream>>>(vals, Wot, out);
}